// Round 12
// baseline (166.803 us; speedup 1.0000x reference)
//
#include <hip/hip_runtime.h>
#include <hip/hip_bf16.h>

#define BB 4096
#define DD 512
#define NB_N2O 512
#define NB_N2N 272
#define NBLK 784

typedef unsigned short u16;
typedef unsigned int u32;
typedef signed char s8;

using f32x4 = __attribute__((ext_vector_type(4))) float;
using i32x4 = __attribute__((ext_vector_type(4))) int;

// int8 quant: q = rint(x_norm * QS); exact i32 dot, s ~= acc / QS^2.
// p = exp2((s-1)*100*log2e + 64) = exp2(acc*CEXPQ + EOFF); lse = 100 - 64*ln2 + ln(sum p)
constexpr float QS = 400.0f;
constexpr float CEXP = 144.26950408889634f;          // 100 * log2(e)
constexpr float CEXPQ = CEXP / (QS * QS);            // dequant folded in
constexpr float EOFF = 64.0f - 144.26950408889634f;  // bias - CEXP
constexpr float LN2 = 0.6931471805599453f;
constexpr float LSE_BASE = 100.0f - 64.0f * 0.6931471805599453f;

__device__ __forceinline__ float wave_sum(float v) {
#pragma unroll
  for (int m = 1; m < 64; m <<= 1) v += __shfl_xor(v, m);
  return v;
}

// async global->LDS, 16B per lane. LDS dest is wave-uniform base + lane*16.
__device__ __forceinline__ void gload16(const void* g, const void* l) {
  __builtin_amdgcn_global_load_lds(
      (const __attribute__((address_space(1))) void*)g,
      (__attribute__((address_space(3))) void*)(const_cast<void*>(l)), 16, 0, 0);
}

// raw barrier (no vmcnt/lgkmcnt drain); memory clobbers pin memory ops to their side
__device__ __forceinline__ void barrier_raw() {
  asm volatile("" ::: "memory");
  __builtin_amdgcn_s_barrier();
  asm volatile("" ::: "memory");
}

__device__ __forceinline__ u32 q4(float a, float b, float c, float d, float s) {
  const int qa = (int)rintf(fminf(fmaxf(a * s, -127.0f), 127.0f));
  const int qb = (int)rintf(fminf(fmaxf(b * s, -127.0f), 127.0f));
  const int qc = (int)rintf(fminf(fmaxf(c * s, -127.0f), 127.0f));
  const int qd = (int)rintf(fminf(fmaxf(d * s, -127.0f), 127.0f));
  return (qa & 0xff) | ((qb & 0xff) << 8) | ((qc & 0xff) << 16) | ((qd & 0xff) << 24);
}

// ---------------- kernel 1: L2-normalize -> int8; zero partial & counter ----------------
__global__ __launch_bounds__(256) void k_norm(const float* __restrict__ feat,
                                              const float* __restrict__ feat_old,
                                              s8* __restrict__ fn8, s8* __restrict__ fo8,
                                              float* __restrict__ pos,
                                              float* __restrict__ partial,
                                              u32* __restrict__ counter) {
  if (threadIdx.x < 4) partial[blockIdx.x * 4 + threadIdx.x] = 0.0f;
  if (blockIdx.x == 0 && threadIdx.x == 4) *counter = 0u;
  const int i = blockIdx.x * 4 + (threadIdx.x >> 6);
  const int t = threadIdx.x & 63;
  const float4 x0 = *(const float4*)(feat + (size_t)i * DD + t * 4);
  const float4 x1 = *(const float4*)(feat + (size_t)i * DD + 256 + t * 4);
  const float4 y0 = *(const float4*)(feat_old + (size_t)i * DD + t * 4);
  const float4 y1 = *(const float4*)(feat_old + (size_t)i * DD + 256 + t * 4);
  float sx = x0.x * x0.x + x0.y * x0.y + x0.z * x0.z + x0.w * x0.w +
             x1.x * x1.x + x1.y * x1.y + x1.z * x1.z + x1.w * x1.w;
  float sy = y0.x * y0.x + y0.y * y0.y + y0.z * y0.z + y0.w * y0.w +
             y1.x * y1.x + y1.y * y1.y + y1.z * y1.z + y1.w * y1.w;
  float sxy = x0.x * y0.x + x0.y * y0.y + x0.z * y0.z + x0.w * y0.w +
              x1.x * y1.x + x1.y * y1.y + x1.z * y1.z + x1.w * y1.w;
  sx = wave_sum(sx);
  sy = wave_sum(sy);
  sxy = wave_sum(sxy);
  const float inx = 1.0f / fmaxf(sqrtf(sx), 1e-12f);
  const float iny = 1.0f / fmaxf(sqrtf(sy), 1e-12f);
  const float sxq = inx * QS, syq = iny * QS;
  u32* px0 = (u32*)(fn8 + (size_t)i * DD + t * 4);
  u32* px1 = (u32*)(fn8 + (size_t)i * DD + 256 + t * 4);
  u32* py0 = (u32*)(fo8 + (size_t)i * DD + t * 4);
  u32* py1 = (u32*)(fo8 + (size_t)i * DD + 256 + t * 4);
  *px0 = q4(x0.x, x0.y, x0.z, x0.w, sxq);
  *px1 = q4(x1.x, x1.y, x1.z, x1.w, sxq);
  *py0 = q4(y0.x, y0.y, y0.z, y0.w, syq);
  *py1 = q4(y1.x, y1.y, y1.z, y1.w, syq);
  if (t == 0) pos[i] = sxy * inx * iny;  // exact fp32 positive logit
}

// ---------------- kernel 2: fused dual-GEMM, n2n-symmetric, atomic row-sums ----------------
// Blocks 0..511: n2o, 256x128 tiles over fn x fo (16mt x 32nt, XCD-swizzled).
// Blocks 512..783: n2n STRICT-UPPER tiles (row-tile 256, col-tile 128, cj >= 2*ri):
//   each unordered pair {i<j} computed ONCE; exp value added to row i (col-reduce)
//   AND row j (transpose row-reduce); predicate (gr<gc)&&(labels differ).
// 512 threads = 8 waves (4M x 2N); wave tile 64x64; acc 4x4 i32x4 = 64 regs.
// R9-proven core: BK=64, LDS dbuf, gload_lds w/ pre-swizzled source, vmcnt(2) gate.
// Row sums accumulate via device-scope fp32 atomics into partial[4096].
// Last-finisher block computes lse rows + mean -> out[0] (fuses old k_final+k_mean).
__global__ __launch_bounds__(512, 4) void k_fused(const s8* __restrict__ fn8,
                                                  const s8* __restrict__ fo8,
                                                  const int* __restrict__ tgt,
                                                  const float* __restrict__ pos,
                                                  float* __restrict__ partial,
                                                  u32* __restrict__ counter,
                                                  float* __restrict__ out) {
  __shared__ __align__(16) s8 lA[2][256 * 64];  // 32 KB
  __shared__ __align__(16) s8 lB[2][128 * 64];  // 16 KB
  __shared__ float red[8];
  __shared__ int fin;

  const int tid = threadIdx.x;
  const int lane = tid & 63;
  const int wid = tid >> 6;  // 0..7
  const int wr = wid & 3;    // M quarter (64 rows)
  const int wc = wid >> 2;   // N half (64 cols)
  const int lrow = lane & 15;
  const int lkg = lane >> 4;

  // ---- block -> tile mapping ----
  const int flat = blockIdx.x;
  const bool isN2O = (flat < NB_N2O);
  int row0, jb;
  const s8* bsrc;
  if (isN2O) {
    const int swz = (flat & 7) * 64 + (flat >> 3);  // XCD-bijective (512%8==0)
    row0 = (swz >> 5) * 256;
    jb = (swz & 31) * 128;
    bsrc = fo8;
  } else {
    int idx = flat - NB_N2O;  // 0..271 -> (ri, cj) with cj >= 2*ri
    int r = 0;
    while (idx >= (r + 1) * (32 - r)) ++r;
    const int cj = 2 * r + (idx - r * (33 - r));
    row0 = r * 256;
    jb = cj * 128;
    bsrc = fn8;
  }

  // staging: chunk = 16 rows x 64 B = 64 lanes x 16 B; source slot pre-swizzled so the
  // linear LDS write lands in read-swizzled position (read slot' = slot ^ ((row>>1)&3)).
  const int crow = lane >> 2;
  const int cofs = 16 * ((lane & 3) ^ ((lane >> 3) & 3));

  auto stageA = [&](s8* dst, int kk) {  // 16 chunks cover 256 A rows; 2/wave
#pragma unroll
    for (int i = 0; i < 2; ++i) {
      const int c = wid * 2 + i;
      gload16(fn8 + (size_t)(row0 + c * 16 + crow) * DD + kk + cofs, dst + c * 1024);
    }
  };
  auto stageB = [&](s8* dst, int kk) {  // 8 chunks cover 128 B rows; 1/wave
    gload16(bsrc + (size_t)(jb + wid * 16 + crow) * DD + kk + cofs, dst + wid * 1024);
  };

  i32x4 acc[4][4];
#pragma unroll
  for (int a = 0; a < 4; ++a)
#pragma unroll
    for (int b = 0; b < 4; ++b) acc[a][b] = (i32x4)(0);

  // prologue: tile 0 (3 loads/wave in flight)
  stageA(lA[0], 0);
  stageB(lB[0], 0);

  for (int t = 0; t < 8; ++t) {
    const int cur = t & 1, nxt = cur ^ 1;
    const s8* cA = lA[cur];
    const s8* cB = lB[cur];

    if (t < 7) {
      stageA(lA[nxt], (t + 1) * 64);
      asm volatile("s_waitcnt vmcnt(2)" ::: "memory");  // tile t's 3 landed; 2 new fly on
    } else {
      asm volatile("s_waitcnt vmcnt(0)" ::: "memory");
    }
    barrier_raw();

    i32x4 av[4], bv[4];
#pragma unroll
    for (int f = 0; f < 4; ++f) {
      const int ar = wr * 64 + f * 16 + lrow;
      av[f] = *(const i32x4*)(cA + ar * 64 + ((lkg ^ ((ar >> 1) & 3)) * 16));
    }
#pragma unroll
    for (int f = 0; f < 4; ++f) {
      const int br = wc * 64 + f * 16 + lrow;
      bv[f] = *(const i32x4*)(cB + br * 64 + ((lkg ^ ((br >> 1) & 3)) * 16));
    }
    if (t < 7) stageB(lB[nxt], (t + 1) * 64);
    __builtin_amdgcn_s_setprio(1);
#pragma unroll
    for (int fr = 0; fr < 4; ++fr)
#pragma unroll
      for (int fc = 0; fc < 4; ++fc)
        acc[fr][fc] = __builtin_amdgcn_mfma_i32_16x16x64_i8(av[fr], bv[fc], acc[fr][fc], 0, 0, 0);
    __builtin_amdgcn_s_setprio(0);
    barrier_raw();
  }

  // ---- epilogue: dequant + masked exp2 -> atomic row sums ----
  int tc[4];
#pragma unroll
  for (int fc = 0; fc < 4; ++fc) tc[fc] = tgt[jb + wc * 64 + fc * 16 + lrow];

  if (isN2O) {
    // col-reduce only; keep diagonal (stands in for the explicit pos column)
#pragma unroll
    for (int fr = 0; fr < 4; ++fr) {
#pragma unroll
      for (int reg = 0; reg < 4; ++reg) {
        const int gr = row0 + wr * 64 + fr * 16 + lkg * 4 + reg;
        const int trv = tgt[gr];
        float s = 0.0f;
#pragma unroll
        for (int fc = 0; fc < 4; ++fc) {
          const int gc = jb + wc * 64 + fc * 16 + lrow;
          const float p = __builtin_amdgcn_exp2f(fmaf((float)acc[fr][fc][reg], CEXPQ, EOFF));
          const bool keep = (trv != tc[fc]) || (gr == gc);
          s += keep ? p : 0.0f;
        }
        s += __shfl_xor(s, 1);
        s += __shfl_xor(s, 2);
        s += __shfl_xor(s, 4);
        s += __shfl_xor(s, 8);
        if (lrow == 0) atomicAdd(&partial[gr], s);
      }
    }
  } else {
    // n2n upper-triangle: keep = (gr<gc) && labels differ; contribute BOTH ways
    float tv[4] = {0.0f, 0.0f, 0.0f, 0.0f};
#pragma unroll
    for (int fr = 0; fr < 4; ++fr) {
#pragma unroll
      for (int reg = 0; reg < 4; ++reg) {
        const int gr = row0 + wr * 64 + fr * 16 + lkg * 4 + reg;
        const int trv = tgt[gr];
        float s = 0.0f;
#pragma unroll
        for (int fc = 0; fc < 4; ++fc) {
          const int gc = jb + wc * 64 + fc * 16 + lrow;
          const float p = __builtin_amdgcn_exp2f(fmaf((float)acc[fr][fc][reg], CEXPQ, EOFF));
          const float pk = ((gr < gc) && (trv != tc[fc])) ? p : 0.0f;
          s += pk;
          tv[fc] += pk;
        }
        s += __shfl_xor(s, 1);
        s += __shfl_xor(s, 2);
        s += __shfl_xor(s, 4);
        s += __shfl_xor(s, 8);
        if (lrow == 0) atomicAdd(&partial[gr], s);  // row i side
      }
    }
    // transpose side: reduce over lkg groups (rows), add to column rows j
#pragma unroll
    for (int fc = 0; fc < 4; ++fc) {
      tv[fc] += __shfl_xor(tv[fc], 16);
      tv[fc] += __shfl_xor(tv[fc], 32);
    }
    if (lkg == 0) {
#pragma unroll
      for (int fc = 0; fc < 4; ++fc)
        atomicAdd(&partial[jb + wc * 64 + fc * 16 + lrow], tv[fc]);
    }
  }

  // ---- last-finisher: fused finalize + mean ----
  __threadfence();
  __syncthreads();
  if (tid == 0) fin = (atomicAdd(counter, 1u) == NBLK - 1) ? 1 : 0;
  __syncthreads();
  if (fin) {
    float s = 0.0f;
#pragma unroll
    for (int q = 0; q < 8; ++q) {
      const int i = q * 512 + tid;
      const float v = atomicAdd(&partial[i], 0.0f);  // coherent cross-XCD read
      s += LSE_BASE + __builtin_amdgcn_logf(v) * LN2 - 100.0f * pos[i];
    }
    s = wave_sum(s);
    if (lane == 0) red[wid] = s;
    __syncthreads();
    if (tid == 0) {
      float tot = 0.0f;
#pragma unroll
      for (int w = 0; w < 8; ++w) tot += red[w];
      out[0] = tot * (1.0f / (float)BB);
    }
  }
}

extern "C" void kernel_launch(void* const* d_in, const int* in_sizes, int n_in,
                              void* d_out, int out_size, void* d_ws, size_t ws_size,
                              hipStream_t stream) {
  const float* feat = (const float*)d_in[0];
  const float* feat_old = (const float*)d_in[1];
  const int* targets = (const int*)d_in[2];
  float* out = (float*)d_out;
  char* ws = (char*)d_ws;

  s8* fn8 = (s8*)ws;                                             // 2 MB
  s8* fo8 = (s8*)(ws + 2u * 1024 * 1024);                        // 2 MB
  float* pos = (float*)(ws + 4u * 1024 * 1024);                  // 16 KB
  float* partial = (float*)(ws + 4u * 1024 * 1024 + 16 * 1024);  // 16 KB
  u32* counter = (u32*)(ws + 4u * 1024 * 1024 + 32 * 1024);      // 4 B

  k_norm<<<BB / 4, 256, 0, stream>>>(feat, feat_old, fn8, fo8, pos, partial, counter);
  k_fused<<<NBLK, 512, 0, stream>>>(fn8, fo8, targets, pos, partial, counter, out);
}

// Round 13
// 133.453 us; speedup vs baseline: 1.2499x; 1.2499x over previous
//
#include <hip/hip_runtime.h>
#include <hip/hip_bf16.h>

#define BB 4096
#define DD 512
#define NB_N2O 512
#define NB_N2N 272
#define NBLK 784
#define NSLOT 80  // 0..31 n2o(nt) | 32..63 n2n-i(cj) | 64..79 n2n-j(ri)

typedef unsigned short u16;
typedef unsigned int u32;
typedef signed char s8;

using f32x4 = __attribute__((ext_vector_type(4))) float;
using i32x4 = __attribute__((ext_vector_type(4))) int;

// int8 quant: q = rint(x_norm * QS); exact i32 dot, s ~= acc / QS^2.
// p = exp2((s-1)*100*log2e + 64) = exp2(acc*CEXPQ + EOFF); lse = 100 - 64*ln2 + ln(sum p)
constexpr float QS = 400.0f;
constexpr float CEXP = 144.26950408889634f;          // 100 * log2(e)
constexpr float CEXPQ = CEXP / (QS * QS);            // dequant folded in
constexpr float EOFF = 64.0f - 144.26950408889634f;  // bias - CEXP
constexpr float LN2 = 0.6931471805599453f;
constexpr float LSE_BASE = 100.0f - 64.0f * 0.6931471805599453f;

__device__ __forceinline__ float wave_sum(float v) {
#pragma unroll
  for (int m = 1; m < 64; m <<= 1) v += __shfl_xor(v, m);
  return v;
}

// async global->LDS, 16B per lane. LDS dest is wave-uniform base + lane*16.
__device__ __forceinline__ void gload16(const void* g, const void* l) {
  __builtin_amdgcn_global_load_lds(
      (const __attribute__((address_space(1))) void*)g,
      (__attribute__((address_space(3))) void*)(const_cast<void*>(l)), 16, 0, 0);
}

// raw barrier (no vmcnt/lgkmcnt drain); memory clobbers pin memory ops to their side
__device__ __forceinline__ void barrier_raw() {
  asm volatile("" ::: "memory");
  __builtin_amdgcn_s_barrier();
  asm volatile("" ::: "memory");
}

__device__ __forceinline__ u32 q4(float a, float b, float c, float d, float s) {
  const int qa = (int)rintf(fminf(fmaxf(a * s, -127.0f), 127.0f));
  const int qb = (int)rintf(fminf(fmaxf(b * s, -127.0f), 127.0f));
  const int qc = (int)rintf(fminf(fmaxf(c * s, -127.0f), 127.0f));
  const int qd = (int)rintf(fminf(fmaxf(d * s, -127.0f), 127.0f));
  return (qa & 0xff) | ((qb & 0xff) << 8) | ((qc & 0xff) << 16) | ((qd & 0xff) << 24);
}

// ---------------- kernel 1: L2-normalize -> int8; zero slot-major partial ----------------
__global__ __launch_bounds__(256) void k_norm(const float* __restrict__ feat,
                                              const float* __restrict__ feat_old,
                                              s8* __restrict__ fn8, s8* __restrict__ fo8,
                                              float* __restrict__ pos,
                                              float* __restrict__ partial) {
  // zero partial[80][4096]: 81920 float4 total = 1024 blocks x 80
  if (threadIdx.x < 80) {
    float4 z; z.x = z.y = z.z = z.w = 0.0f;
    ((float4*)partial)[(size_t)blockIdx.x * 80 + threadIdx.x] = z;
  }
  const int i = blockIdx.x * 4 + (threadIdx.x >> 6);
  const int t = threadIdx.x & 63;
  const float4 x0 = *(const float4*)(feat + (size_t)i * DD + t * 4);
  const float4 x1 = *(const float4*)(feat + (size_t)i * DD + 256 + t * 4);
  const float4 y0 = *(const float4*)(feat_old + (size_t)i * DD + t * 4);
  const float4 y1 = *(const float4*)(feat_old + (size_t)i * DD + 256 + t * 4);
  float sx = x0.x * x0.x + x0.y * x0.y + x0.z * x0.z + x0.w * x0.w +
             x1.x * x1.x + x1.y * x1.y + x1.z * x1.z + x1.w * x1.w;
  float sy = y0.x * y0.x + y0.y * y0.y + y0.z * y0.z + y0.w * y0.w +
             y1.x * y1.x + y1.y * y1.y + y1.z * y1.z + y1.w * y1.w;
  float sxy = x0.x * y0.x + x0.y * y0.y + x0.z * y0.z + x0.w * y0.w +
              x1.x * y1.x + x1.y * y1.y + x1.z * y1.z + x1.w * y1.w;
  sx = wave_sum(sx);
  sy = wave_sum(sy);
  sxy = wave_sum(sxy);
  const float inx = 1.0f / fmaxf(sqrtf(sx), 1e-12f);
  const float iny = 1.0f / fmaxf(sqrtf(sy), 1e-12f);
  const float sxq = inx * QS, syq = iny * QS;
  u32* px0 = (u32*)(fn8 + (size_t)i * DD + t * 4);
  u32* px1 = (u32*)(fn8 + (size_t)i * DD + 256 + t * 4);
  u32* py0 = (u32*)(fo8 + (size_t)i * DD + t * 4);
  u32* py1 = (u32*)(fo8 + (size_t)i * DD + 256 + t * 4);
  *px0 = q4(x0.x, x0.y, x0.z, x0.w, sxq);
  *px1 = q4(x1.x, x1.y, x1.z, x1.w, sxq);
  *py0 = q4(y0.x, y0.y, y0.z, y0.w, syq);
  *py1 = q4(y1.x, y1.y, y1.z, y1.w, syq);
  if (t == 0) pos[i] = sxy * inx * iny;  // exact fp32 positive logit
}

// ---------------- kernel 2: fused dual-GEMM, n2n triangle, slot writes ----------------
// Blocks 0..511: n2o 256x128 tiles (fn x fo), XCD-swizzled. Blocks 512..783: n2n
// strict-upper tiles (ri row-tile of 256, cj col-tile of 128, cj >= 2*ri): each
// unordered pair {i<j} computed ONCE; contributes to row i (col-reduce -> slot 32+cj)
// AND row j (transpose row-reduce across waves via LDS -> slot 64+ri).
// 256 threads = 4 waves (wid = M quarter); wave tile 64x128; acc 4x8 i32x4 = 128 VGPR.
// R9-proven core: BK=64, LDS dbuf 48KB, gload_lds pre-swizzled source, vmcnt(4) gate.
// All partial writes are plain stores to block-private slot regions (no atomics);
// cross-XCD visibility via the kernel boundary before k_final.
__global__ __launch_bounds__(256, 3) void k_fused(const s8* __restrict__ fn8,
                                                  const s8* __restrict__ fo8,
                                                  const int* __restrict__ tgt,
                                                  float* __restrict__ partial) {
  __shared__ __align__(16) s8 lA[2][256 * 64];  // 32 KB
  __shared__ __align__(16) s8 lB[2][128 * 64];  // 16 KB

  const int tid = threadIdx.x;
  const int lane = tid & 63;
  const int wid = tid >> 6;  // 0..3: M quarter (64 rows)
  const int lrow = lane & 15;
  const int lkg = lane >> 4;

  // ---- block -> tile mapping ----
  const int flat = blockIdx.x;
  const bool isN2O = (flat < NB_N2O);
  int row0, jb, ri = 0, cj = 0;
  const s8* bsrc;
  if (isN2O) {
    const int swz = (flat & 7) * 64 + (flat >> 3);  // bijective (512%8==0)
    row0 = (swz >> 5) * 256;
    jb = (swz & 31) * 128;
    bsrc = fo8;
  } else {
    int idx = flat - NB_N2O;  // 0..271 -> (ri, cj) with cj >= 2*ri  [R12-verified]
    int r = 0;
    while (idx >= (r + 1) * (32 - r)) ++r;
    ri = r;
    cj = 2 * r + (idx - r * (33 - r));
    row0 = ri * 256;
    jb = cj * 128;
    bsrc = fn8;
  }

  // staging: chunk = 16 rows x 64 B = 64 lanes x 16 B; source slot pre-swizzled so the
  // linear LDS write lands in read-swizzled position (read slot' = slot ^ ((row>>1)&3)).
  const int crow = lane >> 2;
  const int cofs = 16 * ((lane & 3) ^ ((lane >> 3) & 3));

  auto stageA = [&](s8* dst, int kk) {  // 16 chunks cover 256 A rows; 4/wave
#pragma unroll
    for (int i = 0; i < 4; ++i) {
      const int c = wid * 4 + i;
      gload16(fn8 + (size_t)(row0 + c * 16 + crow) * DD + kk + cofs, dst + c * 1024);
    }
  };
  auto stageB = [&](s8* dst, int kk) {  // 8 chunks cover 128 B rows; 2/wave
#pragma unroll
    for (int i = 0; i < 2; ++i) {
      const int c = wid * 2 + i;
      gload16(bsrc + (size_t)(jb + c * 16 + crow) * DD + kk + cofs, dst + c * 1024);
    }
  };

  i32x4 acc[4][8];
#pragma unroll
  for (int a = 0; a < 4; ++a)
#pragma unroll
    for (int b = 0; b < 8; ++b) acc[a][b] = (i32x4)(0);

  // prologue: tile 0 (6 loads/wave in flight)
  stageA(lA[0], 0);
  stageB(lB[0], 0);

  for (int t = 0; t < 8; ++t) {
    const int cur = t & 1, nxt = cur ^ 1;
    const s8* cA = lA[cur];
    const s8* cB = lB[cur];

    if (t < 7) {
      stageA(lA[nxt], (t + 1) * 64);                  // 4 new; 10 outstanding
      asm volatile("s_waitcnt vmcnt(4)" ::: "memory");  // tile t's 6 landed
    } else {
      asm volatile("s_waitcnt vmcnt(0)" ::: "memory");
    }
    barrier_raw();

    i32x4 av[4], bv[8];
#pragma unroll
    for (int f = 0; f < 4; ++f) {
      const int ar = wid * 64 + f * 16 + lrow;
      av[f] = *(const i32x4*)(cA + ar * 64 + ((lkg ^ ((ar >> 1) & 3)) * 16));
    }
#pragma unroll
    for (int f = 0; f < 8; ++f) {
      const int br = f * 16 + lrow;
      bv[f] = *(const i32x4*)(cB + br * 64 + ((lkg ^ ((br >> 1) & 3)) * 16));
    }
    if (t < 7) stageB(lB[nxt], (t + 1) * 64);
    __builtin_amdgcn_s_setprio(1);
#pragma unroll
    for (int fr = 0; fr < 4; ++fr)
#pragma unroll
      for (int fc = 0; fc < 8; ++fc)
        acc[fr][fc] = __builtin_amdgcn_mfma_i32_16x16x64_i8(av[fr], bv[fc], acc[fr][fc], 0, 0, 0);
    __builtin_amdgcn_s_setprio(0);
    barrier_raw();
  }

  // ---- epilogue: dequant + masked exp2 -> slot-private row sums ----
  int tc[8];
#pragma unroll
  for (int fc = 0; fc < 8; ++fc) tc[fc] = tgt[jb + fc * 16 + lrow];

  if (isN2O) {
    // col-reduce; keep diagonal (stands in for the explicit pos column)
#pragma unroll
    for (int fr = 0; fr < 4; ++fr) {
#pragma unroll
      for (int reg = 0; reg < 4; ++reg) {
        const int gr = row0 + wid * 64 + fr * 16 + lkg * 4 + reg;
        const int trv = tgt[gr];
        float s = 0.0f;
#pragma unroll
        for (int fc = 0; fc < 8; ++fc) {
          const int gc = jb + fc * 16 + lrow;
          const float p = __builtin_amdgcn_exp2f(fmaf((float)acc[fr][fc][reg], CEXPQ, EOFF));
          const bool keep = (trv != tc[fc]) || (gr == gc);
          s += keep ? p : 0.0f;
        }
        s += __shfl_xor(s, 1);
        s += __shfl_xor(s, 2);
        s += __shfl_xor(s, 4);
        s += __shfl_xor(s, 8);
        const int nt = jb >> 7;
        if (lrow == 0) partial[(size_t)nt * BB + gr] = s;  // unique writer
      }
    }
  } else {
    // n2n upper-triangle: keep = (gr<gc) && labels differ; contribute BOTH ways
    float tv[8] = {0, 0, 0, 0, 0, 0, 0, 0};
#pragma unroll
    for (int fr = 0; fr < 4; ++fr) {
#pragma unroll
      for (int reg = 0; reg < 4; ++reg) {
        const int gr = row0 + wid * 64 + fr * 16 + lkg * 4 + reg;
        const int trv = tgt[gr];
        float s = 0.0f;
#pragma unroll
        for (int fc = 0; fc < 8; ++fc) {
          const int gc = jb + fc * 16 + lrow;
          const float p = __builtin_amdgcn_exp2f(fmaf((float)acc[fr][fc][reg], CEXPQ, EOFF));
          const float pk = ((gr < gc) && (trv != tc[fc])) ? p : 0.0f;
          s += pk;
          tv[fc] += pk;
        }
        s += __shfl_xor(s, 1);
        s += __shfl_xor(s, 2);
        s += __shfl_xor(s, 4);
        s += __shfl_xor(s, 8);
        if (lrow == 0) partial[(size_t)(32 + cj) * BB + gr] = s;  // row-i side
      }
    }
    // transpose side: reduce over lkg groups (the wave's 64 rows), combine 4 waves in LDS
#pragma unroll
    for (int fc = 0; fc < 8; ++fc) {
      tv[fc] += __shfl_xor(tv[fc], 16);
      tv[fc] += __shfl_xor(tv[fc], 32);
    }
    float* rsumT = (float*)lA;  // [4 waves][128 cols]; all LDS reads done (loop barrier)
    if (lane < 16) {
#pragma unroll
      for (int fc = 0; fc < 8; ++fc) rsumT[wid * 128 + fc * 16 + lane] = tv[fc];
    }
    asm volatile("s_waitcnt lgkmcnt(0)" ::: "memory");
    barrier_raw();
    if (tid < 128) {
      const float v = rsumT[tid] + rsumT[128 + tid] + rsumT[256 + tid] + rsumT[384 + tid];
      partial[(size_t)(64 + ri) * BB + jb + tid] = v;  // row-j side, unique writer
    }
  }
}

// ---------------- kernel 3: per-row finalize (32 blocks) ----------------
__global__ __launch_bounds__(256) void k_final(const float* __restrict__ partial,
                                               const float* __restrict__ pos,
                                               float* __restrict__ bsum) {
  const int t = threadIdx.x;
  const int r = blockIdx.x * 128 + (t >> 1);
  const int half = t & 1;
  float v = 0.0f;
#pragma unroll
  for (int s = 0; s < 40; ++s) v += partial[(size_t)(half * 40 + s) * BB + r];
  v += __shfl_xor(v, 1);  // combine the two slot-halves of the row
  float contrib = (half == 0)
                      ? (LSE_BASE + __builtin_amdgcn_logf(v) * LN2 - 100.0f * pos[r])
                      : 0.0f;
  contrib = wave_sum(contrib);
  __shared__ float red[4];
  if ((t & 63) == 0) red[t >> 6] = contrib;
  __syncthreads();
  if (t == 0) bsum[blockIdx.x] = (red[0] + red[1]) + (red[2] + red[3]);
}

// ---------------- kernel 4: mean of 32 block sums ----------------
__global__ __launch_bounds__(64) void k_mean(const float* __restrict__ bsum,
                                             float* __restrict__ out) {
  float s = (threadIdx.x < 32) ? bsum[threadIdx.x] : 0.0f;
  s = wave_sum(s);
  if (threadIdx.x == 0) out[0] = s * (1.0f / (float)BB);
}

extern "C" void kernel_launch(void* const* d_in, const int* in_sizes, int n_in,
                              void* d_out, int out_size, void* d_ws, size_t ws_size,
                              hipStream_t stream) {
  const float* feat = (const float*)d_in[0];
  const float* feat_old = (const float*)d_in[1];
  const int* targets = (const int*)d_in[2];
  float* out = (float*)d_out;
  char* ws = (char*)d_ws;

  s8* fn8 = (s8*)ws;                                             // 2 MB
  s8* fo8 = (s8*)(ws + 2u * 1024 * 1024);                        // 2 MB
  float* pos = (float*)(ws + 4u * 1024 * 1024);                  // 16 KB
  float* partial = (float*)(ws + 4u * 1024 * 1024 + 16 * 1024);  // 80*4096*4 = 1.25 MB
  float* bsum = (float*)(ws + 6u * 1024 * 1024);                 // 128 B

  k_norm<<<BB / 4, 256, 0, stream>>>(feat, feat_old, fn8, fo8, pos, partial);
  k_fused<<<NBLK, 256, 0, stream>>>(fn8, fo8, targets, partial);
  k_final<<<32, 256, 0, stream>>>(partial, pos, bsum);
  k_mean<<<1, 64, 0, stream>>>(bsum, out);
}

// Round 14
// 66.313 us; speedup vs baseline: 2.5154x; 2.0125x over previous
//
#include <hip/hip_runtime.h>
#include <hip/hip_bf16.h>

#define BB 4096
#define DD 512
#define NB_N2O 512
#define NB_N2N 272
#define NBLK 784
// partial slots: 0..31 n2o(nt) | 32..63 n2n row-i (cj) | 64..79 n2n row-j (ri)

typedef unsigned short u16;
typedef unsigned int u32;
typedef signed char s8;

using f32x4 = __attribute__((ext_vector_type(4))) float;
using i32x4 = __attribute__((ext_vector_type(4))) int;

// int8 quant: q = rint(x_norm * QS); exact i32 dot, s ~= acc / QS^2.
// p = exp2((s-1)*100*log2e + 64) = exp2(acc*CEXPQ + EOFF); lse = 100 - 64*ln2 + ln(sum p)
constexpr float QS = 400.0f;
constexpr float CEXP = 144.26950408889634f;          // 100 * log2(e)
constexpr float CEXPQ = CEXP / (QS * QS);            // dequant folded in
constexpr float EOFF = 64.0f - 144.26950408889634f;  // bias - CEXP
constexpr float LN2 = 0.6931471805599453f;
constexpr float LSE_BASE = 100.0f - 64.0f * 0.6931471805599453f;

__device__ __forceinline__ float wave_sum(float v) {
#pragma unroll
  for (int m = 1; m < 64; m <<= 1) v += __shfl_xor(v, m);
  return v;
}

// async global->LDS, 16B per lane. LDS dest is wave-uniform base + lane*16.
__device__ __forceinline__ void gload16(const void* g, const void* l) {
  __builtin_amdgcn_global_load_lds(
      (const __attribute__((address_space(1))) void*)g,
      (__attribute__((address_space(3))) void*)(const_cast<void*>(l)), 16, 0, 0);
}

// raw barrier (no vmcnt/lgkmcnt drain); memory clobbers pin memory ops to their side
__device__ __forceinline__ void barrier_raw() {
  asm volatile("" ::: "memory");
  __builtin_amdgcn_s_barrier();
  asm volatile("" ::: "memory");
}

__device__ __forceinline__ u32 q4(float a, float b, float c, float d, float s) {
  const int qa = (int)rintf(fminf(fmaxf(a * s, -127.0f), 127.0f));
  const int qb = (int)rintf(fminf(fmaxf(b * s, -127.0f), 127.0f));
  const int qc = (int)rintf(fminf(fmaxf(c * s, -127.0f), 127.0f));
  const int qd = (int)rintf(fminf(fmaxf(d * s, -127.0f), 127.0f));
  return (qa & 0xff) | ((qb & 0xff) << 8) | ((qc & 0xff) << 16) | ((qd & 0xff) << 24);
}

// ---------------- kernel 1: L2-normalize -> int8; zero slot-major partial ----------------
__global__ __launch_bounds__(256) void k_norm(const float* __restrict__ feat,
                                              const float* __restrict__ feat_old,
                                              s8* __restrict__ fn8, s8* __restrict__ fo8,
                                              float* __restrict__ pos,
                                              float* __restrict__ partial) {
  // zero partial[80][4096]: 81920 float4 = 1024 blocks x 80
  if (threadIdx.x < 80) {
    float4 z; z.x = z.y = z.z = z.w = 0.0f;
    ((float4*)partial)[(size_t)blockIdx.x * 80 + threadIdx.x] = z;
  }
  const int i = blockIdx.x * 4 + (threadIdx.x >> 6);
  const int t = threadIdx.x & 63;
  const float4 x0 = *(const float4*)(feat + (size_t)i * DD + t * 4);
  const float4 x1 = *(const float4*)(feat + (size_t)i * DD + 256 + t * 4);
  const float4 y0 = *(const float4*)(feat_old + (size_t)i * DD + t * 4);
  const float4 y1 = *(const float4*)(feat_old + (size_t)i * DD + 256 + t * 4);
  float sx = x0.x * x0.x + x0.y * x0.y + x0.z * x0.z + x0.w * x0.w +
             x1.x * x1.x + x1.y * x1.y + x1.z * x1.z + x1.w * x1.w;
  float sy = y0.x * y0.x + y0.y * y0.y + y0.z * y0.z + y0.w * y0.w +
             y1.x * y1.x + y1.y * y1.y + y1.z * y1.z + y1.w * y1.w;
  float sxy = x0.x * y0.x + x0.y * y0.y + x0.z * y0.z + x0.w * y0.w +
              x1.x * y1.x + x1.y * y1.y + x1.z * y1.z + x1.w * y1.w;
  sx = wave_sum(sx);
  sy = wave_sum(sy);
  sxy = wave_sum(sxy);
  const float inx = 1.0f / fmaxf(sqrtf(sx), 1e-12f);
  const float iny = 1.0f / fmaxf(sqrtf(sy), 1e-12f);
  const float sxq = inx * QS, syq = iny * QS;
  u32* px0 = (u32*)(fn8 + (size_t)i * DD + t * 4);
  u32* px1 = (u32*)(fn8 + (size_t)i * DD + 256 + t * 4);
  u32* py0 = (u32*)(fo8 + (size_t)i * DD + t * 4);
  u32* py1 = (u32*)(fo8 + (size_t)i * DD + 256 + t * 4);
  *px0 = q4(x0.x, x0.y, x0.z, x0.w, sxq);
  *px1 = q4(x1.x, x1.y, x1.z, x1.w, sxq);
  *py0 = q4(y0.x, y0.y, y0.z, y0.w, syq);
  *py1 = q4(y1.x, y1.y, y1.z, y1.w, syq);
  if (t == 0) pos[i] = sxy * inx * iny;  // exact fp32 positive logit
}

// ---------------- kernel 2: fused dual-GEMM, n2n triangle, slot writes ----------------
// Blocks 0..511: n2o 256x128 tiles (fn x fo), XCD-swizzled. Blocks 512..783: n2n
// strict-upper tiles (ri: 16 row-tiles of 256, cj: 32 col-tiles of 128, cj >= 2*ri):
// each unordered pair {i<j} computed ONCE; contributes to row i (col-reduce, slot 32+cj)
// AND row j (transpose row-reduce across waves via LDS, slot 64+ri).
// 512 threads = 8 waves (wm = wid&3 M-quarter 64 rows; wn = wid>>2 N-half 64 cols);
// acc 4x4 i32x4 = 64 regs (R10-proven register profile, NO spill; R13's 256-thread
// variant spilled acc to scratch -> 218MB scratch writes).
// R9-proven loop: BK=64, LDS dbuf 48KB, gload_lds pre-swizzled source, vmcnt(2) gate.
// All partial writes are plain stores to slot-private regions (no atomics; R12 showed
// per-row device atomics -> 59MB coherence ping-pong, 167us). Cross-XCD visibility
// via the kernel boundary before k_final.
__global__ __launch_bounds__(512, 4) void k_fused(const s8* __restrict__ fn8,
                                                  const s8* __restrict__ fo8,
                                                  const int* __restrict__ tgt,
                                                  float* __restrict__ partial) {
  __shared__ __align__(16) s8 lA[2][256 * 64];  // 32 KB
  __shared__ __align__(16) s8 lB[2][128 * 64];  // 16 KB

  const int tid = threadIdx.x;
  const int lane = tid & 63;
  const int wid = tid >> 6;  // 0..7
  const int wm = wid & 3;    // M quarter (64 rows)
  const int wn = wid >> 2;   // N half (64 cols)
  const int lrow = lane & 15;
  const int lkg = lane >> 4;

  // ---- block -> tile mapping ----
  const int flat = blockIdx.x;
  const bool isN2O = (flat < NB_N2O);
  int row0, jb, ri = 0, cj = 0;
  const s8* bsrc;
  if (isN2O) {
    const int swz = (flat & 7) * 64 + (flat >> 3);  // bijective (512%8==0)
    row0 = (swz >> 5) * 256;
    jb = (swz & 31) * 128;
    bsrc = fo8;
  } else {
    int idx = flat - NB_N2O;  // 0..271 -> (ri, cj), cj >= 2*ri  [R12/R13-verified]
    int r = 0;
    while (idx >= (r + 1) * (32 - r)) ++r;
    ri = r;
    cj = 2 * r + (idx - r * (33 - r));
    row0 = ri * 256;
    jb = cj * 128;
    bsrc = fn8;
  }

  // staging: chunk = 16 rows x 64 B = 64 lanes x 16 B; source slot pre-swizzled so the
  // linear LDS write lands in read-swizzled position (read slot' = slot ^ ((row>>1)&3)).
  const int crow = lane >> 2;
  const int cofs = 16 * ((lane & 3) ^ ((lane >> 3) & 3));

  auto stageA = [&](s8* dst, int kk) {  // 16 chunks cover 256 A rows; 2/wave
#pragma unroll
    for (int i = 0; i < 2; ++i) {
      const int c = wid * 2 + i;
      gload16(fn8 + (size_t)(row0 + c * 16 + crow) * DD + kk + cofs, dst + c * 1024);
    }
  };
  auto stageB = [&](s8* dst, int kk) {  // 8 chunks cover 128 B rows; 1/wave
    gload16(bsrc + (size_t)(jb + wid * 16 + crow) * DD + kk + cofs, dst + wid * 1024);
  };

  i32x4 acc[4][4];
#pragma unroll
  for (int a = 0; a < 4; ++a)
#pragma unroll
    for (int b = 0; b < 4; ++b) acc[a][b] = (i32x4)(0);

  // prologue: tile 0 (3 loads/wave in flight)
  stageA(lA[0], 0);
  stageB(lB[0], 0);

  for (int t = 0; t < 8; ++t) {
    const int cur = t & 1, nxt = cur ^ 1;
    const s8* cA = lA[cur];
    const s8* cB = lB[cur];

    if (t < 7) {
      stageA(lA[nxt], (t + 1) * 64);                  // 2 new; 5 outstanding
      asm volatile("s_waitcnt vmcnt(2)" ::: "memory");  // tile t's 3 landed
    } else {
      asm volatile("s_waitcnt vmcnt(0)" ::: "memory");
    }
    barrier_raw();

    i32x4 av[4], bv[4];
#pragma unroll
    for (int f = 0; f < 4; ++f) {
      const int ar = wm * 64 + f * 16 + lrow;
      av[f] = *(const i32x4*)(cA + ar * 64 + ((lkg ^ ((ar >> 1) & 3)) * 16));
    }
#pragma unroll
    for (int f = 0; f < 4; ++f) {
      const int br = wn * 64 + f * 16 + lrow;
      bv[f] = *(const i32x4*)(cB + br * 64 + ((lkg ^ ((br >> 1) & 3)) * 16));
    }
    if (t < 7) stageB(lB[nxt], (t + 1) * 64);
    __builtin_amdgcn_s_setprio(1);
#pragma unroll
    for (int fr = 0; fr < 4; ++fr)
#pragma unroll
      for (int fc = 0; fc < 4; ++fc)
        acc[fr][fc] = __builtin_amdgcn_mfma_i32_16x16x64_i8(av[fr], bv[fc], acc[fr][fc], 0, 0, 0);
    __builtin_amdgcn_s_setprio(0);
    barrier_raw();
  }

  // ---- epilogue: dequant + masked exp2 -> slot-private row sums ----
  int tc[4];
#pragma unroll
  for (int fc = 0; fc < 4; ++fc) tc[fc] = tgt[jb + wn * 64 + fc * 16 + lrow];
  float* fbuf = (float*)lA;  // 4 KB scratch; loop's trailing barrier freed lA

  if (isN2O) {
    // col-reduce; keep diagonal (stands in for the explicit pos column)
#pragma unroll
    for (int fr = 0; fr < 4; ++fr) {
#pragma unroll
      for (int reg = 0; reg < 4; ++reg) {
        const int gr = row0 + wm * 64 + fr * 16 + lkg * 4 + reg;
        const int trv = tgt[gr];
        float s = 0.0f;
#pragma unroll
        for (int fc = 0; fc < 4; ++fc) {
          const int gc = jb + wn * 64 + fc * 16 + lrow;
          const float p = __builtin_amdgcn_exp2f(fmaf((float)acc[fr][fc][reg], CEXPQ, EOFF));
          const bool keep = (trv != tc[fc]) || (gr == gc);
          s += keep ? p : 0.0f;
        }
        s += __shfl_xor(s, 1);
        s += __shfl_xor(s, 2);
        s += __shfl_xor(s, 4);
        s += __shfl_xor(s, 8);
        if (lrow == 0) fbuf[wn * 256 + wm * 64 + fr * 16 + lkg * 4 + reg] = s;
      }
    }
    asm volatile("s_waitcnt lgkmcnt(0)" ::: "memory");
    barrier_raw();
    if (tid < 256) {
      const int nt = jb >> 7;
      partial[(size_t)nt * BB + row0 + tid] = fbuf[tid] + fbuf[256 + tid];
    }
  } else {
    // n2n upper-triangle: keep = (gr<gc) && labels differ; contribute BOTH ways
    float tv[4] = {0.0f, 0.0f, 0.0f, 0.0f};
#pragma unroll
    for (int fr = 0; fr < 4; ++fr) {
#pragma unroll
      for (int reg = 0; reg < 4; ++reg) {
        const int gr = row0 + wm * 64 + fr * 16 + lkg * 4 + reg;
        const int trv = tgt[gr];
        float s = 0.0f;
#pragma unroll
        for (int fc = 0; fc < 4; ++fc) {
          const int gc = jb + wn * 64 + fc * 16 + lrow;
          const float p = __builtin_amdgcn_exp2f(fmaf((float)acc[fr][fc][reg], CEXPQ, EOFF));
          const float pk = ((gr < gc) && (trv != tc[fc])) ? p : 0.0f;
          s += pk;
          tv[fc] += pk;
        }
        s += __shfl_xor(s, 1);
        s += __shfl_xor(s, 2);
        s += __shfl_xor(s, 4);
        s += __shfl_xor(s, 8);
        if (lrow == 0) fbuf[wn * 256 + wm * 64 + fr * 16 + lkg * 4 + reg] = s;  // row-i
      }
    }
    // transpose side: reduce tv over the wave's 4 lkg row-groups, stash per wave
#pragma unroll
    for (int fc = 0; fc < 4; ++fc) {
      tv[fc] += __shfl_xor(tv[fc], 16);
      tv[fc] += __shfl_xor(tv[fc], 32);
    }
    if (lane < 16) {
#pragma unroll
      for (int fc = 0; fc < 4; ++fc)
        fbuf[512 + wm * 128 + wn * 64 + fc * 16 + lane] = tv[fc];
    }
    asm volatile("s_waitcnt lgkmcnt(0)" ::: "memory");
    barrier_raw();
    if (tid < 256)  // row-i side: combine the two wn halves
      partial[(size_t)(32 + cj) * BB + row0 + tid] = fbuf[tid] + fbuf[256 + tid];
    else if (tid < 384) {  // row-j side: combine the four wm quarters
      const int c = tid - 256;
      const float v = fbuf[512 + c] + fbuf[512 + 128 + c] + fbuf[512 + 256 + c] +
                      fbuf[512 + 384 + c];
      partial[(size_t)(64 + ri) * BB + jb + c] = v;
    }
  }
}

// ---------------- kernel 3: per-row finalize (32 blocks) ----------------
__global__ __launch_bounds__(256) void k_final(const float* __restrict__ partial,
                                               const float* __restrict__ pos,
                                               float* __restrict__ bsum) {
  const int t = threadIdx.x;
  const int r = blockIdx.x * 128 + (t >> 1);
  const int half = t & 1;
  float v = 0.0f;
#pragma unroll
  for (int s = 0; s < 40; ++s) v += partial[(size_t)(half * 40 + s) * BB + r];
  v += __shfl_xor(v, 1);  // combine the two slot-halves of the row
  float contrib = (half == 0)
                      ? (LSE_BASE + __builtin_amdgcn_logf(v) * LN2 - 100.0f * pos[r])
                      : 0.0f;
  contrib = wave_sum(contrib);
  __shared__ float red[4];
  if ((t & 63) == 0) red[t >> 6] = contrib;
  __syncthreads();
  if (t == 0) bsum[blockIdx.x] = (red[0] + red[1]) + (red[2] + red[3]);
}

// ---------------- kernel 4: mean of 32 block sums ----------------
__global__ __launch_bounds__(64) void k_mean(const float* __restrict__ bsum,
                                             float* __restrict__ out) {
  float s = (threadIdx.x < 32) ? bsum[threadIdx.x] : 0.0f;
  s = wave_sum(s);
  if (threadIdx.x == 0) out[0] = s * (1.0f / (float)BB);
}

extern "C" void kernel_launch(void* const* d_in, const int* in_sizes, int n_in,
                              void* d_out, int out_size, void* d_ws, size_t ws_size,
                              hipStream_t stream) {
  const float* feat = (const float*)d_in[0];
  const float* feat_old = (const float*)d_in[1];
  const int* targets = (const int*)d_in[2];
  float* out = (float*)d_out;
  char* ws = (char*)d_ws;

  s8* fn8 = (s8*)ws;                                             // 2 MB
  s8* fo8 = (s8*)(ws + 2u * 1024 * 1024);                        // 2 MB
  float* pos = (float*)(ws + 4u * 1024 * 1024);                  // 16 KB
  float* partial = (float*)(ws + 4u * 1024 * 1024 + 16 * 1024);  // 80*4096*4 = 1.25 MB
  float* bsum = (float*)(ws + 6u * 1024 * 1024);                 // 128 B

  k_norm<<<BB / 4, 256, 0, stream>>>(feat, feat_old, fn8, fo8, pos, partial);
  k_fused<<<NBLK, 512, 0, stream>>>(fn8, fo8, targets, partial);
  k_final<<<32, 256, 0, stream>>>(partial, pos, bsum);
  k_mean<<<1, 64, 0, stream>>>(bsum, out);
}